// Round 4
// baseline (730.713 us; speedup 1.0000x reference)
//
#include <hip/hip_runtime.h>
#include <hip/hip_bf16.h>

#define NB 8
#define SEQ 512
#define DMODEL 1024
#define NHEAD 16
#define HDIM 64
typedef __hip_bfloat16 bf16;

// ------------------------------------------------- QKV GEMM + bias + RoPE
// C(4096x3072) = X(4096x1024) @ W(1024x3072) + b ; epilogue: inline-trig RoPE
// on Q,K, scatter to (B,H,S,Dh) bf16 buffers. One 64-col tile == one (c,h).
__global__ __launch_bounds__(256)
void qkv_gemm_k(const float* __restrict__ X, const float* __restrict__ W,
                const float* __restrict__ bias,
                bf16* __restrict__ Qb, bf16* __restrict__ Kb, bf16* __restrict__ Vb) {
    __shared__ float As[64][17];                 // [m][k], +1 pad
    __shared__ __align__(16) float Bs[16][64];   // [k][n]
    __shared__ float Cs[64][64];
    int tid = threadIdx.x;
    int tx = tid & 15, ty = tid >> 4;
    int m0 = blockIdx.y * 64, n0 = blockIdx.x * 64;
    int ar = tid >> 2, ac = (tid & 3) * 4;
    int br = tid >> 4, bc = (tid & 15) * 4;
    float acc[4][4] = {};
    for (int k0 = 0; k0 < DMODEL; k0 += 16) {
        __syncthreads();
        float4 av = *(const float4*)&X[(size_t)(m0 + ar) * DMODEL + k0 + ac];
        As[ar][ac + 0] = av.x; As[ar][ac + 1] = av.y;
        As[ar][ac + 2] = av.z; As[ar][ac + 3] = av.w;
        *(float4*)&Bs[br][bc] = *(const float4*)&W[(size_t)(k0 + br) * 3072 + n0 + bc];
        __syncthreads();
        #pragma unroll
        for (int kk = 0; kk < 16; ++kk) {
            float a[4], b[4];
            #pragma unroll
            for (int i = 0; i < 4; ++i) a[i] = As[ty * 4 + i][kk];
            float4 bv = *(const float4*)&Bs[kk][tx * 4];
            b[0] = bv.x; b[1] = bv.y; b[2] = bv.z; b[3] = bv.w;
            #pragma unroll
            for (int i = 0; i < 4; ++i)
                #pragma unroll
                for (int j = 0; j < 4; ++j)
                    acc[i][j] += a[i] * b[j];
        }
    }
    #pragma unroll
    for (int i = 0; i < 4; ++i)
        #pragma unroll
        for (int j = 0; j < 4; ++j)
            Cs[ty * 4 + i][tx * 4 + j] = acc[i][j] + bias[n0 + tx * 4 + j];
    __syncthreads();
    int c = n0 >> 10;            // 0=Q 1=K 2=V
    int h = (n0 & 1023) >> 6;
    bf16* dst = (c == 0) ? Qb : (c == 1) ? Kb : Vb;
    for (int idx = tid; idx < 64 * 32; idx += 256) {   // pairs (p, p+32)
        int r = idx >> 5, p = idx & 31;
        int m = m0 + r;
        int b = m >> 9, s = m & 511;
        size_t base = ((size_t)(b * NHEAD + h) * SEQ + s) * HDIM;
        float v1 = Cs[r][p], v2 = Cs[r][p + 32];
        float o1, o2;
        if (c == 2) {
            o1 = v1; o2 = v2;
        } else {
            float freq = expf(-(float)p * 0.28782313662425574f); // 10000^(-p/32)
            float sv, cv;
            sincosf((float)s * freq, &sv, &cv);
            o1 = v1 * cv - v2 * sv;
            o2 = v1 * sv + v2 * cv;
        }
        dst[base + p]      = __float2bfloat16(o1);
        dst[base + p + 32] = __float2bfloat16(o2);
    }
}

// ------------------------------------------------------- flash-style attention
// grid = (B*H)*8 blocks; each block: 64 q-rows, iterate 8 k/v tiles of 64.
// Ps aliases Ks (extra barrier between S-compute and P-store) to fit LDS.
__global__ __launch_bounds__(256)
void attn_k(const bf16* __restrict__ Qb, const bf16* __restrict__ Kb,
            const bf16* __restrict__ Vb, float* __restrict__ Ab) {
    __shared__ __align__(16) float Qs[64][68];
    __shared__ __align__(16) float Ks[64][68];   // doubles as Ps
    __shared__ __align__(16) float Vs[64][68];
    int tid = threadIdx.x;
    int tx = tid & 15, ty = tid >> 4;
    int bh = blockIdx.x >> 3, qt = blockIdx.x & 7;
    const bf16* Qp = Qb + ((size_t)bh * SEQ + qt * 64) * HDIM;
    const bf16* Kp = Kb + (size_t)bh * SEQ * HDIM;
    const bf16* Vp = Vb + (size_t)bh * SEQ * HDIM;
    for (int i = tid; i < 512; i += 256) {       // 64 rows x 8 groups of 8 bf16
        int r = i >> 3, c8 = (i & 7) * 8;
        uint4 t = *(const uint4*)&Qp[(size_t)r * 64 + c8];
        float* q = &Qs[r][c8];
        q[0] = __uint_as_float(t.x << 16); q[1] = __uint_as_float(t.x & 0xffff0000u);
        q[2] = __uint_as_float(t.y << 16); q[3] = __uint_as_float(t.y & 0xffff0000u);
        q[4] = __uint_as_float(t.z << 16); q[5] = __uint_as_float(t.z & 0xffff0000u);
        q[6] = __uint_as_float(t.w << 16); q[7] = __uint_as_float(t.w & 0xffff0000u);
    }
    float m_[4], l_[4], O_[4][4];
    #pragma unroll
    for (int i = 0; i < 4; ++i) {
        m_[i] = -1e30f; l_[i] = 0.f;
        #pragma unroll
        for (int j = 0; j < 4; ++j) O_[i][j] = 0.f;
    }
    for (int kt = 0; kt < 8; ++kt) {
        __syncthreads();   // prev PV done with Ks(=Ps)/Vs; Q store also fenced here
        for (int i = tid; i < 512; i += 256) {
            int r = i >> 3, c8 = (i & 7) * 8;
            uint4 t = *(const uint4*)&Kp[(size_t)(kt * 64 + r) * 64 + c8];
            float* kq = &Ks[r][c8];
            kq[0] = __uint_as_float(t.x << 16); kq[1] = __uint_as_float(t.x & 0xffff0000u);
            kq[2] = __uint_as_float(t.y << 16); kq[3] = __uint_as_float(t.y & 0xffff0000u);
            kq[4] = __uint_as_float(t.z << 16); kq[5] = __uint_as_float(t.z & 0xffff0000u);
            kq[6] = __uint_as_float(t.w << 16); kq[7] = __uint_as_float(t.w & 0xffff0000u);
            uint4 v = *(const uint4*)&Vp[(size_t)(kt * 64 + r) * 64 + c8];
            float* vq = &Vs[r][c8];
            vq[0] = __uint_as_float(v.x << 16); vq[1] = __uint_as_float(v.x & 0xffff0000u);
            vq[2] = __uint_as_float(v.y << 16); vq[3] = __uint_as_float(v.y & 0xffff0000u);
            vq[4] = __uint_as_float(v.z << 16); vq[5] = __uint_as_float(v.z & 0xffff0000u);
            vq[6] = __uint_as_float(v.w << 16); vq[7] = __uint_as_float(v.w & 0xffff0000u);
        }
        __syncthreads();
        // S = (Q K^T) * 0.125
        float sacc[4][4] = {};
        #pragma unroll 4
        for (int k4 = 0; k4 < 64; k4 += 4) {
            float a[4][4], b[4][4];
            #pragma unroll
            for (int i = 0; i < 4; ++i) {
                float4 t = *(const float4*)&Qs[ty * 4 + i][k4];
                a[i][0] = t.x; a[i][1] = t.y; a[i][2] = t.z; a[i][3] = t.w;
            }
            #pragma unroll
            for (int j = 0; j < 4; ++j) {
                float4 t = *(const float4*)&Ks[tx * 4 + j][k4];
                b[j][0] = t.x; b[j][1] = t.y; b[j][2] = t.z; b[j][3] = t.w;
            }
            #pragma unroll
            for (int i = 0; i < 4; ++i)
                #pragma unroll
                for (int j = 0; j < 4; ++j)
                    #pragma unroll
                    for (int kk = 0; kk < 4; ++kk)
                        sacc[i][j] += a[i][kk] * b[j][kk];
        }
        __syncthreads();   // everyone done READING Ks before it becomes Ps
        // online softmax (row stats across the 16 tx lanes)
        float p[4][4];
        #pragma unroll
        for (int i = 0; i < 4; ++i) {
            #pragma unroll
            for (int j = 0; j < 4; ++j) sacc[i][j] *= 0.125f;
            float tm = fmaxf(fmaxf(sacc[i][0], sacc[i][1]), fmaxf(sacc[i][2], sacc[i][3]));
            tm = fmaxf(tm, __shfl_xor(tm, 1));
            tm = fmaxf(tm, __shfl_xor(tm, 2));
            tm = fmaxf(tm, __shfl_xor(tm, 4));
            tm = fmaxf(tm, __shfl_xor(tm, 8));
            float mn = fmaxf(m_[i], tm);
            float sc = __expf(m_[i] - mn);
            float ts = 0.f;
            #pragma unroll
            for (int j = 0; j < 4; ++j) { p[i][j] = __expf(sacc[i][j] - mn); ts += p[i][j]; }
            ts += __shfl_xor(ts, 1);
            ts += __shfl_xor(ts, 2);
            ts += __shfl_xor(ts, 4);
            ts += __shfl_xor(ts, 8);
            l_[i] = l_[i] * sc + ts;
            m_[i] = mn;
            #pragma unroll
            for (int j = 0; j < 4; ++j) O_[i][j] *= sc;
        }
        float (*Ps)[68] = Ks;
        #pragma unroll
        for (int i = 0; i < 4; ++i)
            #pragma unroll
            for (int j = 0; j < 4; ++j)
                Ps[ty * 4 + i][tx * 4 + j] = p[i][j];
        __syncthreads();
        // O += P @ V
        #pragma unroll 4
        for (int k4 = 0; k4 < 64; k4 += 4) {
            float pr[4][4], vr[4][4];
            #pragma unroll
            for (int i = 0; i < 4; ++i) {
                float4 t = *(const float4*)&Ps[ty * 4 + i][k4];
                pr[i][0] = t.x; pr[i][1] = t.y; pr[i][2] = t.z; pr[i][3] = t.w;
            }
            #pragma unroll
            for (int kk = 0; kk < 4; ++kk) {
                float4 t = *(const float4*)&Vs[k4 + kk][tx * 4];
                vr[kk][0] = t.x; vr[kk][1] = t.y; vr[kk][2] = t.z; vr[kk][3] = t.w;
            }
            #pragma unroll
            for (int i = 0; i < 4; ++i)
                #pragma unroll
                for (int j = 0; j < 4; ++j)
                    #pragma unroll
                    for (int kk = 0; kk < 4; ++kk)
                        O_[i][j] += pr[i][kk] * vr[kk][j];
        }
    }
    // epilogue: normalize, write to (B,S,D) layout for the output GEMM
    int b = bh >> 4, h = bh & 15;
    #pragma unroll
    for (int i = 0; i < 4; ++i) {
        float inv = 1.0f / l_[i];
        int s = qt * 64 + ty * 4 + i;
        float4 o;
        o.x = O_[i][0] * inv; o.y = O_[i][1] * inv;
        o.z = O_[i][2] * inv; o.w = O_[i][3] * inv;
        *(float4*)&Ab[((size_t)b * SEQ + s) * DMODEL + h * 64 + tx * 4] = o;
    }
}

// ------------------------------------------------- out GEMM + bias -> FP32
__global__ __launch_bounds__(256)
void out_gemm_k(const float* __restrict__ A, const float* __restrict__ W,
                const float* __restrict__ bias, float* __restrict__ out) {
    __shared__ float As[64][17];
    __shared__ __align__(16) float Bs[16][64];
    int tid = threadIdx.x;
    int tx = tid & 15, ty = tid >> 4;
    int m0 = blockIdx.y * 64, n0 = blockIdx.x * 64;
    int ar = tid >> 2, ac = (tid & 3) * 4;
    int br = tid >> 4, bc = (tid & 15) * 4;
    float acc[4][4] = {};
    for (int k0 = 0; k0 < DMODEL; k0 += 16) {
        __syncthreads();
        float4 av = *(const float4*)&A[(size_t)(m0 + ar) * DMODEL + k0 + ac];
        As[ar][ac + 0] = av.x; As[ar][ac + 1] = av.y;
        As[ar][ac + 2] = av.z; As[ar][ac + 3] = av.w;
        *(float4*)&Bs[br][bc] = *(const float4*)&W[(size_t)(k0 + br) * DMODEL + n0 + bc];
        __syncthreads();
        #pragma unroll
        for (int kk = 0; kk < 16; ++kk) {
            float a[4], b[4];
            #pragma unroll
            for (int i = 0; i < 4; ++i) a[i] = As[ty * 4 + i][kk];
            float4 bv = *(const float4*)&Bs[kk][tx * 4];
            b[0] = bv.x; b[1] = bv.y; b[2] = bv.z; b[3] = bv.w;
            #pragma unroll
            for (int i = 0; i < 4; ++i)
                #pragma unroll
                for (int j = 0; j < 4; ++j)
                    acc[i][j] += a[i] * b[j];
        }
    }
    #pragma unroll
    for (int i = 0; i < 4; ++i) {
        float4 o;
        o.x = acc[i][0] + bias[n0 + tx * 4 + 0];
        o.y = acc[i][1] + bias[n0 + tx * 4 + 1];
        o.z = acc[i][2] + bias[n0 + tx * 4 + 2];
        o.w = acc[i][3] + bias[n0 + tx * 4 + 3];
        *(float4*)&out[(size_t)(m0 + ty * 4 + i) * DMODEL + n0 + tx * 4] = o;
    }
}

extern "C" void kernel_launch(void* const* d_in, const int* in_sizes, int n_in,
                              void* d_out, int out_size, void* d_ws, size_t ws_size,
                              hipStream_t stream) {
    // Resolve inputs by element count (all distinct) — robust to ordering.
    const float *x = nullptr, *Wqkv = nullptr, *bqkv = nullptr,
                *Wout = nullptr, *bout = nullptr;
    for (int i = 0; i < n_in; ++i) {
        switch (in_sizes[i]) {
            case NB * SEQ * DMODEL:      x    = (const float*)d_in[i]; break; // 4194304
            case DMODEL * 3 * DMODEL:    Wqkv = (const float*)d_in[i]; break; // 3145728
            case 3 * DMODEL:             bqkv = (const float*)d_in[i]; break; // 3072
            case DMODEL * DMODEL:        Wout = (const float*)d_in[i]; break; // 1048576
            case DMODEL:                 bout = (const float*)d_in[i]; break; // 1024
        }
    }
    if (!x)    x    = (const float*)d_in[0];
    if (!Wqkv) Wqkv = (const float*)d_in[1];
    if (!bqkv) bqkv = (const float*)d_in[2];
    if (!Wout) Wout = (const float*)d_in[3];
    if (!bout) bout = (const float*)d_in[4];
    float* out = (float*)d_out;   // reference output dtype is float32

    // ws layout (40 MB total): Ab fp32 16MB | Qb,Kb,Vb bf16 8MB each
    const size_t HSZ = (size_t)NB * NHEAD * SEQ * HDIM;   // 4,194,304 elems
    float* Ab = (float*)d_ws;
    bf16* Qb = (bf16*)(Ab + HSZ);
    bf16* Kb = Qb + HSZ;
    bf16* Vb = Kb + HSZ;

    qkv_gemm_k<<<dim3(48, 64), 256, 0, stream>>>(x, Wqkv, bqkv, Qb, Kb, Vb);
    attn_k<<<NB * NHEAD * 8, 256, 0, stream>>>(Qb, Kb, Vb, Ab);
    out_gemm_k<<<dim3(16, 64), 256, 0, stream>>>(Ab, Wout, bout, out);
}

// Round 6
// 293.862 us; speedup vs baseline: 2.4866x; 2.4866x over previous
//
#include <hip/hip_runtime.h>
#include <hip/hip_bf16.h>

#define NB 8
#define SEQ 512
#define DMODEL 1024
#define NHEAD 16
#define HDIM 64
typedef __hip_bfloat16 bf16;
typedef __attribute__((ext_vector_type(8))) short short8;
typedef __attribute__((ext_vector_type(4))) float f32x4;

__device__ __forceinline__ void glds16(const void* g, void* l) {
    __builtin_amdgcn_global_load_lds(
        (const __attribute__((address_space(1))) unsigned int*)g,
        (__attribute__((address_space(3))) unsigned int*)l, 16, 0, 0);
}

// ---------------- fp32 -> bf16 cast (X), 8 elems/thread
__global__ __launch_bounds__(256)
void cast_bf16_k(const float* __restrict__ X, bf16* __restrict__ Xb) {
    int i = (blockIdx.x * 256 + threadIdx.x) * 8;
    float4 v0 = *(const float4*)&X[i];
    float4 v1 = *(const float4*)&X[i + 4];
    bf16 o[8];
    o[0] = __float2bfloat16(v0.x); o[1] = __float2bfloat16(v0.y);
    o[2] = __float2bfloat16(v0.z); o[3] = __float2bfloat16(v0.w);
    o[4] = __float2bfloat16(v1.x); o[5] = __float2bfloat16(v1.y);
    o[6] = __float2bfloat16(v1.z); o[7] = __float2bfloat16(v1.w);
    *(uint4*)&Xb[i] = *(uint4*)o;
}

// ---------------- fp32 [R][C] -> bf16 [C][R] transpose (W -> W^T)
__global__ __launch_bounds__(256)
void transpose_cast_k(const float* __restrict__ W, bf16* __restrict__ Wt,
                      int R, int C) {
    __shared__ float t[64][65];
    int k0 = blockIdx.y * 64, n0 = blockIdx.x * 64;
    int c = threadIdx.x & 63, r = threadIdx.x >> 6;
    #pragma unroll 4
    for (int i = 0; i < 16; ++i)
        t[r + i * 4][c] = W[(size_t)(k0 + r + i * 4) * C + n0 + c];
    __syncthreads();
    #pragma unroll 4
    for (int i = 0; i < 16; ++i)
        Wt[(size_t)(n0 + r + i * 4) * R + k0 + c] = __float2bfloat16(t[c][r + i * 4]);
}

// ================= MFMA GEMM mainloop (shared pattern) ====================
// C[128x128] per block, 4 waves (2x2), BK=64, 16 K-steps over K=1024.
// A: [M][1024] bf16 row-major; B: [N][1024] bf16 row-major (i.e. W^T).
// LDS tiles [128 rows][64 k] with chunk-XOR swizzle: slot s of row r holds
// global k-chunk s^(r&7); staged via global_load_lds w=16 from pre-swizzled
// global addresses (rule #21: linear dest + inverse-swz source + swz read).
#define GEMM_MAINLOOP(Agp, Bgp)                                               \
    __shared__ __align__(16) short Asm[128 * 64];                             \
    __shared__ __align__(16) short Bsm[128 * 64];                             \
    int tid = threadIdx.x;                                                    \
    int lane = tid & 63, wid = tid >> 6;                                      \
    int wr = wid >> 1, wc = wid & 1;                                          \
    int lj = lane & 15, li = lane >> 4;                                       \
    f32x4 acc[4][4] = {};                                                     \
    for (int ks = 0; ks < 16; ++ks) {                                         \
        int k0 = ks * 64;                                                     \
        int srow = (lane >> 3), ssl = lane & 7;                               \
        _Pragma("unroll")                                                     \
        for (int q = 0; q < 4; ++q) {                                         \
            int seg = wid * 4 + q;                                            \
            int row = seg * 8 + srow;                                         \
            int cg = ssl ^ (row & 7);                                         \
            glds16(Agp + ((size_t)(m0 + row) * 1024 + k0 + cg * 8),           \
                   (char*)Asm + seg * 1024);                                  \
            glds16(Bgp + ((size_t)(n0 + row) * 1024 + k0 + cg * 8),           \
                   (char*)Bsm + seg * 1024);                                  \
        }                                                                     \
        __syncthreads();                                                      \
        _Pragma("unroll")                                                     \
        for (int kk = 0; kk < 2; ++kk) {                                      \
            short8 af[4], bf[4];                                              \
            _Pragma("unroll")                                                 \
            for (int mf = 0; mf < 4; ++mf) {                                  \
                int r = wr * 64 + mf * 16 + lj;                               \
                int ck = kk * 4 + li;                                         \
                af[mf] = *(const short8*)((const char*)Asm +                  \
                          (r * 128 + ((ck ^ (r & 7)) * 16)));                 \
            }                                                                 \
            _Pragma("unroll")                                                 \
            for (int nf = 0; nf < 4; ++nf) {                                  \
                int r = wc * 64 + nf * 16 + lj;                               \
                int ck = kk * 4 + li;                                         \
                bf[nf] = *(const short8*)((const char*)Bsm +                  \
                          (r * 128 + ((ck ^ (r & 7)) * 16)));                 \
            }                                                                 \
            _Pragma("unroll")                                                 \
            for (int mf = 0; mf < 4; ++mf)                                    \
                _Pragma("unroll")                                             \
                for (int nf = 0; nf < 4; ++nf)                                \
                    acc[mf][nf] = __builtin_amdgcn_mfma_f32_16x16x32_bf16(    \
                        af[mf], bf[nf], acc[mf][nf], 0, 0, 0);                \
        }                                                                     \
        __syncthreads();                                                      \
    }

// ---------------- QKV GEMM (M=4096, N=3072) + bias + RoPE epilogue
__global__ __launch_bounds__(256)
void qkv_mfma_k(const bf16* __restrict__ Xb, const bf16* __restrict__ Wt,
                const float* __restrict__ bias,
                bf16* __restrict__ Qb, bf16* __restrict__ Kb, bf16* __restrict__ Vb) {
    int m0 = blockIdx.y * 128, n0 = blockIdx.x * 128;
    GEMM_MAINLOOP(Xb, Wt)
    // epilogue: wave's 64-col span = exactly one (c,h); RoPE pairs are
    // fragments (nf, nf+2) since col-within-frag = lane&15 for both.
    int ncol = n0 + wc * 64;
    int c = ncol >> 10;
    int h = (ncol & 1023) >> 6;
    bf16* dst = (c == 0) ? Qb : (c == 1) ? Kb : Vb;
    #pragma unroll
    for (int nf = 0; nf < 2; ++nf) {
        int p = nf * 16 + lj;
        float b1 = bias[ncol + p], b2 = bias[ncol + p + 32];
        float freq = __expf(-(float)p * 0.28782313662425574f); // 10000^(-p/32)
        #pragma unroll
        for (int mf = 0; mf < 4; ++mf) {
            #pragma unroll
            for (int j = 0; j < 4; ++j) {
                int m = m0 + wr * 64 + mf * 16 + li * 4 + j;
                int bb = m >> 9, s = m & 511;
                float v1 = acc[mf][nf][j] + b1;
                float v2 = acc[mf][nf + 2][j] + b2;
                float o1, o2;
                if (c == 2) { o1 = v1; o2 = v2; }
                else {
                    float sv, cv;
                    sincosf((float)s * freq, &sv, &cv);
                    o1 = v1 * cv - v2 * sv;
                    o2 = v1 * sv + v2 * cv;
                }
                size_t base = ((size_t)(bb * NHEAD + h) * SEQ + s) * HDIM;
                dst[base + p]      = __float2bfloat16(o1);
                dst[base + p + 32] = __float2bfloat16(o2);
            }
        }
    }
}

// ---------------- out GEMM (M=4096, N=1024) + bias -> fp32
__global__ __launch_bounds__(256)
void out_mfma_k(const bf16* __restrict__ Ab, const bf16* __restrict__ Wt,
                const float* __restrict__ bias, float* __restrict__ out) {
    int m0 = blockIdx.y * 128, n0 = blockIdx.x * 128;
    GEMM_MAINLOOP(Ab, Wt)
    int col0 = n0 + wc * 64;
    #pragma unroll
    for (int nf = 0; nf < 4; ++nf) {
        int col = col0 + nf * 16 + lj;
        float bv = bias[col];
        #pragma unroll
        for (int mf = 0; mf < 4; ++mf)
            #pragma unroll
            for (int j = 0; j < 4; ++j) {
                int m = m0 + wr * 64 + mf * 16 + li * 4 + j;
                out[(size_t)m * DMODEL + col] = acc[mf][nf][j] + bv;
            }
    }
}

// ------------------------------------------------------- flash-style attention
// (unchanged known-good fp32 kernel; epilogue writes bf16 for out_mfma)
__global__ __launch_bounds__(256)
void attn_k(const bf16* __restrict__ Qb, const bf16* __restrict__ Kb,
            const bf16* __restrict__ Vb, bf16* __restrict__ Ab) {
    __shared__ __align__(16) float Qs[64][68];
    __shared__ __align__(16) float Ks[64][68];   // doubles as Ps
    __shared__ __align__(16) float Vs[64][68];
    int tid = threadIdx.x;
    int tx = tid & 15, ty = tid >> 4;
    int bh = blockIdx.x >> 3, qt = blockIdx.x & 7;
    const bf16* Qp = Qb + ((size_t)bh * SEQ + qt * 64) * HDIM;
    const bf16* Kp = Kb + (size_t)bh * SEQ * HDIM;
    const bf16* Vp = Vb + (size_t)bh * SEQ * HDIM;
    for (int i = tid; i < 512; i += 256) {
        int r = i >> 3, c8 = (i & 7) * 8;
        uint4 t = *(const uint4*)&Qp[(size_t)r * 64 + c8];
        float* q = &Qs[r][c8];
        q[0] = __uint_as_float(t.x << 16); q[1] = __uint_as_float(t.x & 0xffff0000u);
        q[2] = __uint_as_float(t.y << 16); q[3] = __uint_as_float(t.y & 0xffff0000u);
        q[4] = __uint_as_float(t.z << 16); q[5] = __uint_as_float(t.z & 0xffff0000u);
        q[6] = __uint_as_float(t.w << 16); q[7] = __uint_as_float(t.w & 0xffff0000u);
    }
    float m_[4], l_[4], O_[4][4];
    #pragma unroll
    for (int i = 0; i < 4; ++i) {
        m_[i] = -1e30f; l_[i] = 0.f;
        #pragma unroll
        for (int j = 0; j < 4; ++j) O_[i][j] = 0.f;
    }
    for (int kt = 0; kt < 8; ++kt) {
        __syncthreads();
        for (int i = tid; i < 512; i += 256) {
            int r = i >> 3, c8 = (i & 7) * 8;
            uint4 t = *(const uint4*)&Kp[(size_t)(kt * 64 + r) * 64 + c8];
            float* kq = &Ks[r][c8];
            kq[0] = __uint_as_float(t.x << 16); kq[1] = __uint_as_float(t.x & 0xffff0000u);
            kq[2] = __uint_as_float(t.y << 16); kq[3] = __uint_as_float(t.y & 0xffff0000u);
            kq[4] = __uint_as_float(t.z << 16); kq[5] = __uint_as_float(t.z & 0xffff0000u);
            kq[6] = __uint_as_float(t.w << 16); kq[7] = __uint_as_float(t.w & 0xffff0000u);
            uint4 v = *(const uint4*)&Vp[(size_t)(kt * 64 + r) * 64 + c8];
            float* vq = &Vs[r][c8];
            vq[0] = __uint_as_float(v.x << 16); vq[1] = __uint_as_float(v.x & 0xffff0000u);
            vq[2] = __uint_as_float(v.y << 16); vq[3] = __uint_as_float(v.y & 0xffff0000u);
            vq[4] = __uint_as_float(v.z << 16); vq[5] = __uint_as_float(v.z & 0xffff0000u);
            vq[6] = __uint_as_float(v.w << 16); vq[7] = __uint_as_float(v.w & 0xffff0000u);
        }
        __syncthreads();
        float sacc[4][4] = {};
        #pragma unroll 4
        for (int k4 = 0; k4 < 64; k4 += 4) {
            float a[4][4], b[4][4];
            #pragma unroll
            for (int i = 0; i < 4; ++i) {
                float4 t = *(const float4*)&Qs[ty * 4 + i][k4];
                a[i][0] = t.x; a[i][1] = t.y; a[i][2] = t.z; a[i][3] = t.w;
            }
            #pragma unroll
            for (int j = 0; j < 4; ++j) {
                float4 t = *(const float4*)&Ks[tx * 4 + j][k4];
                b[j][0] = t.x; b[j][1] = t.y; b[j][2] = t.z; b[j][3] = t.w;
            }
            #pragma unroll
            for (int i = 0; i < 4; ++i)
                #pragma unroll
                for (int j = 0; j < 4; ++j)
                    #pragma unroll
                    for (int kk = 0; kk < 4; ++kk)
                        sacc[i][j] += a[i][kk] * b[j][kk];
        }
        __syncthreads();
        float p[4][4];
        #pragma unroll
        for (int i = 0; i < 4; ++i) {
            #pragma unroll
            for (int j = 0; j < 4; ++j) sacc[i][j] *= 0.125f;
            float tm = fmaxf(fmaxf(sacc[i][0], sacc[i][1]), fmaxf(sacc[i][2], sacc[i][3]));
            tm = fmaxf(tm, __shfl_xor(tm, 1));
            tm = fmaxf(tm, __shfl_xor(tm, 2));
            tm = fmaxf(tm, __shfl_xor(tm, 4));
            tm = fmaxf(tm, __shfl_xor(tm, 8));
            float mn = fmaxf(m_[i], tm);
            float sc = __expf(m_[i] - mn);
            float ts = 0.f;
            #pragma unroll
            for (int j = 0; j < 4; ++j) { p[i][j] = __expf(sacc[i][j] - mn); ts += p[i][j]; }
            ts += __shfl_xor(ts, 1);
            ts += __shfl_xor(ts, 2);
            ts += __shfl_xor(ts, 4);
            ts += __shfl_xor(ts, 8);
            l_[i] = l_[i] * sc + ts;
            m_[i] = mn;
            #pragma unroll
            for (int j = 0; j < 4; ++j) O_[i][j] *= sc;
        }
        float (*Ps)[68] = Ks;
        #pragma unroll
        for (int i = 0; i < 4; ++i)
            #pragma unroll
            for (int j = 0; j < 4; ++j)
                Ps[ty * 4 + i][tx * 4 + j] = p[i][j];
        __syncthreads();
        #pragma unroll 4
        for (int k4 = 0; k4 < 64; k4 += 4) {
            float pr[4][4], vr[4][4];
            #pragma unroll
            for (int i = 0; i < 4; ++i) {
                float4 t = *(const float4*)&Ps[ty * 4 + i][k4];
                pr[i][0] = t.x; pr[i][1] = t.y; pr[i][2] = t.z; pr[i][3] = t.w;
            }
            #pragma unroll
            for (int kk = 0; kk < 4; ++kk) {
                float4 t = *(const float4*)&Vs[k4 + kk][tx * 4];
                vr[kk][0] = t.x; vr[kk][1] = t.y; vr[kk][2] = t.z; vr[kk][3] = t.w;
            }
            #pragma unroll
            for (int i = 0; i < 4; ++i)
                #pragma unroll
                for (int j = 0; j < 4; ++j)
                    #pragma unroll
                    for (int kk = 0; kk < 4; ++kk)
                        O_[i][j] += pr[i][kk] * vr[kk][j];
        }
    }
    int b = bh >> 4, h = bh & 15;
    #pragma unroll
    for (int i = 0; i < 4; ++i) {
        float inv = 1.0f / l_[i];
        int s = qt * 64 + ty * 4 + i;
        union { bf16 b[4]; ushort4 u; } pk;
        pk.b[0] = __float2bfloat16(O_[i][0] * inv);
        pk.b[1] = __float2bfloat16(O_[i][1] * inv);
        pk.b[2] = __float2bfloat16(O_[i][2] * inv);
        pk.b[3] = __float2bfloat16(O_[i][3] * inv);
        *(ushort4*)&Ab[((size_t)b * SEQ + s) * DMODEL + h * 64 + tx * 4] = pk.u;
    }
}

extern "C" void kernel_launch(void* const* d_in, const int* in_sizes, int n_in,
                              void* d_out, int out_size, void* d_ws, size_t ws_size,
                              hipStream_t stream) {
    const float *x = nullptr, *Wqkv = nullptr, *bqkv = nullptr,
                *Wout = nullptr, *bout = nullptr;
    for (int i = 0; i < n_in; ++i) {
        switch (in_sizes[i]) {
            case NB * SEQ * DMODEL:   x    = (const float*)d_in[i]; break;
            case DMODEL * 3 * DMODEL: Wqkv = (const float*)d_in[i]; break;
            case 3 * DMODEL:          bqkv = (const float*)d_in[i]; break;
            case DMODEL * DMODEL:     Wout = (const float*)d_in[i]; break;
            case DMODEL:              bout = (const float*)d_in[i]; break;
        }
    }
    if (!x)    x    = (const float*)d_in[0];
    if (!Wqkv) Wqkv = (const float*)d_in[1];
    if (!bqkv) bqkv = (const float*)d_in[2];
    if (!Wout) Wout = (const float*)d_in[3];
    if (!bout) bout = (const float*)d_in[4];
    float* out = (float*)d_out;

    // ws layout, 40 MB peak (same as round-4 proven footprint):
    // [0,8M)   Xb bf16  — dead after qkv_mfma; Ab (bf16) aliases it
    // [8,14M)  Wqkv_t bf16 | [14,16M) Wout_t bf16
    // [16,24M) Qb | [24,32M) Kb | [32,40M) Vb
    char* ws = (char*)d_ws;
    bf16* Xb     = (bf16*)(ws);
    bf16* Ab     = (bf16*)(ws);                    // aliases Xb (stream-ordered)
    bf16* Wqkv_t = (bf16*)(ws + 8388608);
    bf16* Wout_t = (bf16*)(ws + 14680064);
    bf16* Qb     = (bf16*)(ws + 16777216);
    bf16* Kb     = (bf16*)(ws + 25165824);
    bf16* Vb     = (bf16*)(ws + 33554432);

    cast_bf16_k<<<2048, 256, 0, stream>>>(x, Xb);
    transpose_cast_k<<<dim3(48, 16), 256, 0, stream>>>(Wqkv, Wqkv_t, DMODEL, 3 * DMODEL);
    transpose_cast_k<<<dim3(16, 16), 256, 0, stream>>>(Wout, Wout_t, DMODEL, DMODEL);
    qkv_mfma_k<<<dim3(24, 32), 256, 0, stream>>>(Xb, Wqkv_t, bqkv, Qb, Kb, Vb);
    attn_k<<<NB * NHEAD * 8, 256, 0, stream>>>(Qb, Kb, Vb, Ab);
    out_mfma_k<<<dim3(8, 32), 256, 0, stream>>>(Ab, Wout_t, bout, out);
}

// Round 7
// 202.157 us; speedup vs baseline: 3.6146x; 1.4536x over previous
//
#include <hip/hip_runtime.h>
#include <hip/hip_bf16.h>

#define NB 8
#define SEQ 512
#define DMODEL 1024
#define NHEAD 16
#define HDIM 64
typedef __hip_bfloat16 bf16;
typedef __attribute__((ext_vector_type(8))) short short8;
typedef __attribute__((ext_vector_type(4))) float f32x4;

__device__ __forceinline__ void glds16(const void* g, void* l) {
    __builtin_amdgcn_global_load_lds(
        (const __attribute__((address_space(1))) unsigned int*)g,
        (__attribute__((address_space(3))) unsigned int*)l, 16, 0, 0);
}

// ---------------- fp32 -> bf16 cast (X), 8 elems/thread
__global__ __launch_bounds__(256)
void cast_bf16_k(const float* __restrict__ X, bf16* __restrict__ Xb) {
    int i = (blockIdx.x * 256 + threadIdx.x) * 8;
    float4 v0 = *(const float4*)&X[i];
    float4 v1 = *(const float4*)&X[i + 4];
    bf16 o[8];
    o[0] = __float2bfloat16(v0.x); o[1] = __float2bfloat16(v0.y);
    o[2] = __float2bfloat16(v0.z); o[3] = __float2bfloat16(v0.w);
    o[4] = __float2bfloat16(v1.x); o[5] = __float2bfloat16(v1.y);
    o[6] = __float2bfloat16(v1.z); o[7] = __float2bfloat16(v1.w);
    *(uint4*)&Xb[i] = *(uint4*)o;
}

// ---------------- fp32 [R][C] -> bf16 [C][R] transpose (W -> W^T)
__global__ __launch_bounds__(256)
void transpose_cast_k(const float* __restrict__ W, bf16* __restrict__ Wt,
                      int R, int C) {
    __shared__ float t[64][65];
    int k0 = blockIdx.y * 64, n0 = blockIdx.x * 64;
    int c = threadIdx.x & 63, r = threadIdx.x >> 6;
    #pragma unroll 4
    for (int i = 0; i < 16; ++i)
        t[r + i * 4][c] = W[(size_t)(k0 + r + i * 4) * C + n0 + c];
    __syncthreads();
    #pragma unroll 4
    for (int i = 0; i < 16; ++i)
        Wt[(size_t)(n0 + r + i * 4) * R + k0 + c] = __float2bfloat16(t[c][r + i * 4]);
}

// ================= MFMA GEMM mainloop (shared pattern) ====================
#define GEMM_MAINLOOP(Agp, Bgp)                                               \
    __shared__ __align__(16) short Asm[128 * 64];                             \
    __shared__ __align__(16) short Bsm[128 * 64];                             \
    int tid = threadIdx.x;                                                    \
    int lane = tid & 63, wid = tid >> 6;                                      \
    int wr = wid >> 1, wc = wid & 1;                                          \
    int lj = lane & 15, li = lane >> 4;                                       \
    f32x4 acc[4][4] = {};                                                     \
    for (int ks = 0; ks < 16; ++ks) {                                         \
        int k0 = ks * 64;                                                     \
        int srow = (lane >> 3), ssl = lane & 7;                               \
        _Pragma("unroll")                                                     \
        for (int q = 0; q < 4; ++q) {                                         \
            int seg = wid * 4 + q;                                            \
            int row = seg * 8 + srow;                                         \
            int cg = ssl ^ (row & 7);                                         \
            glds16(Agp + ((size_t)(m0 + row) * 1024 + k0 + cg * 8),           \
                   (char*)Asm + seg * 1024);                                  \
            glds16(Bgp + ((size_t)(n0 + row) * 1024 + k0 + cg * 8),           \
                   (char*)Bsm + seg * 1024);                                  \
        }                                                                     \
        __syncthreads();                                                      \
        _Pragma("unroll")                                                     \
        for (int kk = 0; kk < 2; ++kk) {                                      \
            short8 af[4], bf[4];                                              \
            _Pragma("unroll")                                                 \
            for (int mf = 0; mf < 4; ++mf) {                                  \
                int r = wr * 64 + mf * 16 + lj;                               \
                int ck = kk * 4 + li;                                         \
                af[mf] = *(const short8*)((const char*)Asm +                  \
                          (r * 128 + ((ck ^ (r & 7)) * 16)));                 \
            }                                                                 \
            _Pragma("unroll")                                                 \
            for (int nf = 0; nf < 4; ++nf) {                                  \
                int r = wc * 64 + nf * 16 + lj;                               \
                int ck = kk * 4 + li;                                         \
                bf[nf] = *(const short8*)((const char*)Bsm +                  \
                          (r * 128 + ((ck ^ (r & 7)) * 16)));                 \
            }                                                                 \
            _Pragma("unroll")                                                 \
            for (int mf = 0; mf < 4; ++mf)                                    \
                _Pragma("unroll")                                             \
                for (int nf = 0; nf < 4; ++nf)                                \
                    acc[mf][nf] = __builtin_amdgcn_mfma_f32_16x16x32_bf16(    \
                        af[mf], bf[nf], acc[mf][nf], 0, 0, 0);                \
        }                                                                     \
        __syncthreads();                                                      \
    }

// ---------------- QKV GEMM (M=4096, N=3072) + bias + RoPE epilogue
// V is written TRANSPOSED: Vt[b,h,d,s] so attention can stage it as B-operand.
__global__ __launch_bounds__(256)
void qkv_mfma_k(const bf16* __restrict__ Xb, const bf16* __restrict__ Wt,
                const float* __restrict__ bias,
                bf16* __restrict__ Qb, bf16* __restrict__ Kb, bf16* __restrict__ Vt) {
    int m0 = blockIdx.y * 128, n0 = blockIdx.x * 128;
    GEMM_MAINLOOP(Xb, Wt)
    int ncol = n0 + wc * 64;
    int c = ncol >> 10;
    int h = (ncol & 1023) >> 6;
    #pragma unroll
    for (int nf = 0; nf < 2; ++nf) {
        int p = nf * 16 + lj;
        float b1 = bias[ncol + p], b2 = bias[ncol + p + 32];
        float freq = __expf(-(float)p * 0.28782313662425574f); // 10000^(-p/32)
        #pragma unroll
        for (int mf = 0; mf < 4; ++mf) {
            #pragma unroll
            for (int j = 0; j < 4; ++j) {
                int m = m0 + wr * 64 + mf * 16 + li * 4 + j;
                int bb = m >> 9, s = m & 511;
                float v1 = acc[mf][nf][j] + b1;
                float v2 = acc[mf][nf + 2][j] + b2;
                if (c == 2) {
                    size_t tb = (size_t)(bb * NHEAD + h) * HDIM;
                    Vt[(tb + p) * SEQ + s]      = __float2bfloat16(v1);
                    Vt[(tb + p + 32) * SEQ + s] = __float2bfloat16(v2);
                } else {
                    float sv, cv;
                    sincosf((float)s * freq, &sv, &cv);
                    float o1 = v1 * cv - v2 * sv;
                    float o2 = v1 * sv + v2 * cv;
                    bf16* dst = (c == 0) ? Qb : Kb;
                    size_t base = ((size_t)(bb * NHEAD + h) * SEQ + s) * HDIM;
                    dst[base + p]      = __float2bfloat16(o1);
                    dst[base + p + 32] = __float2bfloat16(o2);
                }
            }
        }
    }
}

// ---------------- out GEMM (M=4096, N=1024) + bias -> fp32
__global__ __launch_bounds__(256)
void out_mfma_k(const bf16* __restrict__ Ab, const bf16* __restrict__ Wt,
                const float* __restrict__ bias, float* __restrict__ out) {
    int m0 = blockIdx.y * 128, n0 = blockIdx.x * 128;
    GEMM_MAINLOOP(Ab, Wt)
    int col0 = n0 + wc * 64;
    #pragma unroll
    for (int nf = 0; nf < 4; ++nf) {
        int col = col0 + nf * 16 + lj;
        float bv = bias[col];
        #pragma unroll
        for (int mf = 0; mf < 4; ++mf)
            #pragma unroll
            for (int j = 0; j < 4; ++j) {
                int m = m0 + wr * 64 + mf * 16 + li * 4 + j;
                out[(size_t)m * DMODEL + col] = acc[mf][nf][j] + bv;
            }
    }
}

// ---------------- MFMA flash attention -----------------------------------
// grid = (B*H)*8; block = 64 q-rows of one (b,h); 4 waves, wave w owns rows
// w*16..w*16+16 (softmax stats wave-local). K-tiles of 64; Q,K,V^T staged
// via swizzled glds16; P via wave-local swizzled LDS round-trip.
__global__ __launch_bounds__(256)
void attn_mfma_k(const bf16* __restrict__ Qb, const bf16* __restrict__ Kb,
                 const bf16* __restrict__ Vt, bf16* __restrict__ Ab) {
    __shared__ __align__(16) short Qsm[64 * 64];
    __shared__ __align__(16) short Ksm[64 * 64];
    __shared__ __align__(16) short Vsm[64 * 64];
    __shared__ __align__(16) short Psm[64 * 64];
    int tid = threadIdx.x;
    int lane = tid & 63, wid = tid >> 6;
    int lj = lane & 15, li = lane >> 4;
    int bh = blockIdx.x >> 3, qt = blockIdx.x & 7;
    const bf16* Qp = Qb + ((size_t)bh * SEQ + qt * 64) * HDIM;
    const bf16* Kp = Kb + (size_t)bh * SEQ * HDIM;
    const bf16* Vp = Vt + (size_t)bh * HDIM * SEQ;
    int srow = lane >> 3, ssl = lane & 7;
    #pragma unroll
    for (int q = 0; q < 2; ++q) {                 // stage Q once (swizzled)
        int seg = wid * 2 + q;
        int row = seg * 8 + srow;
        int cg = ssl ^ (row & 7);
        glds16(Qp + ((size_t)row * 64 + cg * 8), (char*)Qsm + seg * 1024);
    }
    float m_[4], l_[4];
    f32x4 acc_o[4] = {};                          // [nf] d-frags; j indexes rows
    #pragma unroll
    for (int j = 0; j < 4; ++j) { m_[j] = -1e30f; l_[j] = 0.f; }
    __syncthreads();
    for (int kt = 0; kt < 8; ++kt) {
        #pragma unroll
        for (int q = 0; q < 2; ++q) {             // stage K-tile + V^T-tile
            int seg = wid * 2 + q;
            int row = seg * 8 + srow;
            int cg = ssl ^ (row & 7);
            glds16(Kp + ((size_t)(kt * 64 + row) * 64 + cg * 8),
                   (char*)Ksm + seg * 1024);
            glds16(Vp + ((size_t)row * SEQ + kt * 64 + cg * 8),
                   (char*)Vsm + seg * 1024);
        }
        __syncthreads();
        // S = Q K^T  (wave rows = wid*16..+16, cols nf*16+lj)
        f32x4 sacc[4] = {};
        #pragma unroll
        for (int kk = 0; kk < 2; ++kk) {
            int r = wid * 16 + lj;
            int ck = kk * 4 + li;
            short8 af = *(const short8*)((const char*)Qsm +
                         (r * 128 + ((ck ^ (r & 7)) * 16)));
            #pragma unroll
            for (int nf = 0; nf < 4; ++nf) {
                int rb = nf * 16 + lj;
                short8 kf = *(const short8*)((const char*)Ksm +
                             (rb * 128 + ((ck ^ (rb & 7)) * 16)));
                sacc[nf] = __builtin_amdgcn_mfma_f32_16x16x32_bf16(af, kf, sacc[nf], 0, 0, 0);
            }
        }
        // online softmax: row = wid*16 + li*4 + j
        float p[4][4];
        #pragma unroll
        for (int j = 0; j < 4; ++j) {
            float s0 = sacc[0][j] * 0.125f, s1 = sacc[1][j] * 0.125f;
            float s2 = sacc[2][j] * 0.125f, s3 = sacc[3][j] * 0.125f;
            float tm = fmaxf(fmaxf(s0, s1), fmaxf(s2, s3));
            tm = fmaxf(tm, __shfl_xor(tm, 1));
            tm = fmaxf(tm, __shfl_xor(tm, 2));
            tm = fmaxf(tm, __shfl_xor(tm, 4));
            tm = fmaxf(tm, __shfl_xor(tm, 8));
            float mn = fmaxf(m_[j], tm);
            float sc = __expf(m_[j] - mn);
            p[0][j] = __expf(s0 - mn); p[1][j] = __expf(s1 - mn);
            p[2][j] = __expf(s2 - mn); p[3][j] = __expf(s3 - mn);
            float ts = p[0][j] + p[1][j] + p[2][j] + p[3][j];
            ts += __shfl_xor(ts, 1); ts += __shfl_xor(ts, 2);
            ts += __shfl_xor(ts, 4); ts += __shfl_xor(ts, 8);
            l_[j] = l_[j] * sc + ts;
            m_[j] = mn;
            acc_o[0][j] *= sc; acc_o[1][j] *= sc;
            acc_o[2][j] *= sc; acc_o[3][j] *= sc;
        }
        // P -> LDS (bf16, swizzled; wave-local rows — no cross-wave hazard)
        #pragma unroll
        for (int nf = 0; nf < 4; ++nf)
            #pragma unroll
            for (int j = 0; j < 4; ++j) {
                int row = wid * 16 + li * 4 + j;
                int col = nf * 16 + lj;
                int cl = col >> 3;
                *(bf16*)((char*)Psm + row * 128 + ((cl ^ (row & 7)) * 16) +
                         (col & 7) * 2) = __float2bfloat16(p[nf][j]);
            }
        // O += P V   (A = own P rows, B = V^T rows = d)
        #pragma unroll
        for (int kk = 0; kk < 2; ++kk) {
            int r = wid * 16 + lj;
            int ck = kk * 4 + li;
            short8 pa = *(const short8*)((const char*)Psm +
                         (r * 128 + ((ck ^ (r & 7)) * 16)));
            #pragma unroll
            for (int nf = 0; nf < 4; ++nf) {
                int rb = nf * 16 + lj;
                short8 vf = *(const short8*)((const char*)Vsm +
                             (rb * 128 + ((ck ^ (rb & 7)) * 16)));
                acc_o[nf] = __builtin_amdgcn_mfma_f32_16x16x32_bf16(pa, vf, acc_o[nf], 0, 0, 0);
            }
        }
        __syncthreads();   // all waves done reading Ks/Vs before next stage
    }
    // epilogue: normalize, write bf16 to (B,S,D) for out_mfma
    int b = bh >> 4, h = bh & 15;
    #pragma unroll
    for (int j = 0; j < 4; ++j) {
        float inv = 1.0f / l_[j];
        int s = qt * 64 + wid * 16 + li * 4 + j;
        #pragma unroll
        for (int nf = 0; nf < 4; ++nf) {
            int d = nf * 16 + lj;
            Ab[((size_t)b * SEQ + s) * DMODEL + h * 64 + d] =
                __float2bfloat16(acc_o[nf][j] * inv);
        }
    }
}

extern "C" void kernel_launch(void* const* d_in, const int* in_sizes, int n_in,
                              void* d_out, int out_size, void* d_ws, size_t ws_size,
                              hipStream_t stream) {
    const float *x = nullptr, *Wqkv = nullptr, *bqkv = nullptr,
                *Wout = nullptr, *bout = nullptr;
    for (int i = 0; i < n_in; ++i) {
        switch (in_sizes[i]) {
            case NB * SEQ * DMODEL:   x    = (const float*)d_in[i]; break;
            case DMODEL * 3 * DMODEL: Wqkv = (const float*)d_in[i]; break;
            case 3 * DMODEL:          bqkv = (const float*)d_in[i]; break;
            case DMODEL * DMODEL:     Wout = (const float*)d_in[i]; break;
            case DMODEL:              bout = (const float*)d_in[i]; break;
        }
    }
    if (!x)    x    = (const float*)d_in[0];
    if (!Wqkv) Wqkv = (const float*)d_in[1];
    if (!bqkv) bqkv = (const float*)d_in[2];
    if (!Wout) Wout = (const float*)d_in[3];
    if (!bout) bout = (const float*)d_in[4];
    float* out = (float*)d_out;

    // ws layout, 40 MB peak (proven footprint):
    // [0,8M)   Xb bf16 — dead after qkv_mfma; Ab (bf16) aliases it
    // [8,14M)  Wqkv_t | [14,16M) Wout_t | [16,24M) Qb | [24,32M) Kb | [32,40M) Vt
    char* ws = (char*)d_ws;
    bf16* Xb     = (bf16*)(ws);
    bf16* Ab     = (bf16*)(ws);                    // aliases Xb (stream-ordered)
    bf16* Wqkv_t = (bf16*)(ws + 8388608);
    bf16* Wout_t = (bf16*)(ws + 14680064);
    bf16* Qb     = (bf16*)(ws + 16777216);
    bf16* Kb     = (bf16*)(ws + 25165824);
    bf16* Vt     = (bf16*)(ws + 33554432);         // transposed: [b,h,d,s]

    cast_bf16_k<<<2048, 256, 0, stream>>>(x, Xb);
    transpose_cast_k<<<dim3(48, 16), 256, 0, stream>>>(Wqkv, Wqkv_t, DMODEL, 3 * DMODEL);
    transpose_cast_k<<<dim3(16, 16), 256, 0, stream>>>(Wout, Wout_t, DMODEL, DMODEL);
    qkv_mfma_k<<<dim3(24, 32), 256, 0, stream>>>(Xb, Wqkv_t, bqkv, Qb, Kb, Vt);
    attn_mfma_k<<<NB * NHEAD * 8, 256, 0, stream>>>(Qb, Kb, Vt, Ab);
    out_mfma_k<<<dim3(8, 32), 256, 0, stream>>>(Ab, Wout_t, bout, out);
}